// Round 1
// baseline (355.545 us; speedup 1.0000x reference)
//
#include <hip/hip_runtime.h>

typedef unsigned int   u32;
typedef unsigned short u16;

typedef __bf16 bf16x8 __attribute__((ext_vector_type(8)));
typedef float  f32x4  __attribute__((ext_vector_type(4)));

#define M_TOK 128

__device__ __forceinline__ u16 f2bf(float f) {
    u32 u = __builtin_bit_cast(u32, f);
    return (u16)((u + 0x8000u) >> 16);   // round-half-up to bf16
}
__device__ __forceinline__ float bf2f(u16 h) {
    u32 u = ((u32)h) << 16;
    return __builtin_bit_cast(float, u);
}

// ---------------------------------------------------------------------------
// RMSNorm: one block per token row (4096 cols), fp32 in -> bf16 out
// ---------------------------------------------------------------------------
__launch_bounds__(256)
__global__ void rmsnorm_k(const float* __restrict__ in, const float* __restrict__ w,
                          u16* __restrict__ out) {
    const int row = blockIdx.x;
    const float* x = in + (size_t)row * 4096;
    float ss = 0.f;
#pragma unroll
    for (int j = 0; j < 16; ++j) {
        float v = x[threadIdx.x + 256 * j];
        ss += v * v;
    }
#pragma unroll
    for (int off = 32; off > 0; off >>= 1) ss += __shfl_down(ss, off, 64);
    __shared__ float ws4[4];
    if ((threadIdx.x & 63) == 0) ws4[threadIdx.x >> 6] = ss;
    __syncthreads();
    float total = ws4[0] + ws4[1] + ws4[2] + ws4[3];
    float r = rsqrtf(total * (1.f / 4096.f) + 1e-6f);
    u16* o = out + (size_t)row * 4096;
#pragma unroll
    for (int j = 0; j < 16; ++j) {
        int i = threadIdx.x + 256 * j;
        o[i] = f2bf(x[i] * r * w[i]);
    }
}

// ---------------------------------------------------------------------------
// AWQ GEMM: A (bf16, 128 x K row-major, stride Astride) @ dequant(W) (K x N)
// Writes bf16 split-K partials: part[sk][128][N].
// Tile: BM=128, BN=128, BK=32; 4 waves, each 64x64 via 4x4 mfma_16x16x32_bf16.
// ---------------------------------------------------------------------------
__launch_bounds__(256)
__global__ void gemm_awq(const u16* __restrict__ A, const int* __restrict__ qw,
                         const int* __restrict__ qz, const float* __restrict__ sc,
                         u16* __restrict__ part,
                         int Astride, int qws, int scs, int N, int kchunk) {
    __shared__ u16 Al[128 * 40];   // [m][k], stride 40 (pad) -> 80B rows
    __shared__ u16 Bl[128 * 40];   // [n][k], stride 40

    const int tid = threadIdx.x;
    const int n0 = blockIdx.x * 128;
    const int sk = blockIdx.y;
    const int kc0 = sk * kchunk;
    const int steps = kchunk >> 5;

    const int w    = tid >> 6;
    const int lane = tid & 63;
    const int wr = (w >> 1) * 64;       // wave m-base
    const int wc = (w & 1) * 64;        // wave n-base
    const int q   = lane >> 4;
    const int l16 = lane & 15;

    // dequant mapping: thread handles k-pair (2 rows of qw) x 8 columns
    const int kp = tid & 15;            // k-pair index 0..15  (k = 2*kp, 2*kp+1)
    const int p  = tid >> 4;            // packed-col 0..15 -> n = p*8+j
    const int pc = (n0 >> 3) + p;

    // A staging mapping: 512 chunks of 16B; each thread does 2
    const int ar0 = tid >> 2,          ac0 = (tid & 3) * 8;
    const int ar1 = (tid + 256) >> 2,  ac1 = ((tid + 256) & 3) * 8;

    f32x4 acc[4][4] = {};

    const u32 M4 = 0x0F0F0F0Fu;

    for (int s = 0; s < steps; ++s) {
        const int k0 = kc0 + s * 32;

        // ---- stage A tile (128 x 32 bf16) ----
        *(uint4*)&Al[ar0 * 40 + ac0] = *(const uint4*)&A[(size_t)ar0 * Astride + k0 + ac0];
        *(uint4*)&Al[ar1 * 40 + ac1] = *(const uint4*)&A[(size_t)ar1 * Astride + k0 + ac1];

        // ---- dequant B tile (32 x 128) into Bl[n][k] ----
        {
            const int k = k0 + kp * 2;
            const int g = k >> 7;
            const u32 w0 = (u32)qw[(size_t)k * qws + pc];
            const u32 w1 = (u32)qw[(size_t)(k + 1) * qws + pc];
            const u32 zv = (u32)qz[(size_t)g * qws + pc];
            const float* scp = sc + (size_t)g * scs + n0 + p * 8;
            float s_[8];
            *(float4*)&s_[0] = *(const float4*)&scp[0];
            *(float4*)&s_[4] = *(const float4*)&scp[4];

            // biased bytes: each byte = 16 + w - z  in [1,31]; no carries
            const u32 be  = 0x10101010u - (zv & M4);
            const u32 bo  = 0x10101010u - ((zv >> 4) & M4);
            const u32 d0e = (w0 & M4) + be;
            const u32 d0o = ((w0 >> 4) & M4) + bo;
            const u32 d1e = (w1 & M4) + be;
            const u32 d1o = ((w1 >> 4) & M4) + bo;

            u16* brow = &Bl[kp * 2];
            auto emit = [&](int j, u32 a0, u32 a1, int b) {
                const float scj = s_[j];
                const float off = -16.f * scj;
                float f0 = fmaf((float)((a0 >> (8 * b)) & 0xFFu), scj, off);
                float f1 = fmaf((float)((a1 >> (8 * b)) & 0xFFu), scj, off);
                u32 u0 = __builtin_bit_cast(u32, f0) + 0x8000u;
                u32 u1 = __builtin_bit_cast(u32, f1) + 0x8000u;
                *(u32*)&brow[(p * 8 + j) * 40] = __builtin_amdgcn_perm(u1, u0, 0x07060302u);
            };
            // nibble order: even nibbles (shift 0,8,16,24) -> j = 0,4,1,5
            //               odd  nibbles (shift 4,12,20,28) -> j = 2,6,3,7
            emit(0, d0e, d1e, 0); emit(4, d0e, d1e, 1);
            emit(1, d0e, d1e, 2); emit(5, d0e, d1e, 3);
            emit(2, d0o, d1o, 0); emit(6, d0o, d1o, 1);
            emit(3, d0o, d1o, 2); emit(7, d0o, d1o, 3);
        }
        __syncthreads();

        // ---- fragments + MFMA ----
        bf16x8 af[4], bv[4];
#pragma unroll
        for (int mt = 0; mt < 4; ++mt)
            af[mt] = *(const bf16x8*)&Al[(wr + mt * 16 + l16) * 40 + q * 8];
#pragma unroll
        for (int nt = 0; nt < 4; ++nt)
            bv[nt] = *(const bf16x8*)&Bl[(wc + nt * 16 + l16) * 40 + q * 8];
#pragma unroll
        for (int mt = 0; mt < 4; ++mt)
#pragma unroll
            for (int nt = 0; nt < 4; ++nt)
                acc[mt][nt] = __builtin_amdgcn_mfma_f32_16x16x32_bf16(
                    af[mt], bv[nt], acc[mt][nt], 0, 0, 0);
        __syncthreads();
    }

    // ---- epilogue: bf16 partial store ----
    u16* pp = part + (size_t)sk * M_TOK * N;
#pragma unroll
    for (int mt = 0; mt < 4; ++mt) {
#pragma unroll
        for (int nt = 0; nt < 4; ++nt) {
            const int n = n0 + wc + nt * 16 + l16;
#pragma unroll
            for (int r = 0; r < 4; ++r) {
                const int m = wr + mt * 16 + q * 4 + r;
                pp[(size_t)m * N + n] = f2bf(acc[mt][nt][r]);
            }
        }
    }
}

// ---------------------------------------------------------------------------
// Reduce split-K bf16 partials -> bf16
// ---------------------------------------------------------------------------
__launch_bounds__(256)
__global__ void reduce_bf16(const u16* __restrict__ part, u16* __restrict__ out,
                            int total, int SK) {
    const int i = blockIdx.x * 256 + threadIdx.x;
    float s = 0.f;
    for (int k = 0; k < SK; ++k) s += bf2f(part[(size_t)k * total + i]);
    out[i] = f2bf(s);
}

// Reduce split-K bf16 partials + fp32 residual -> fp32
__launch_bounds__(256)
__global__ void reduce_add_f32(const u16* __restrict__ part, const float* __restrict__ resin,
                               float* __restrict__ out, int total, int SK) {
    const int i = blockIdx.x * 256 + threadIdx.x;
    float s = resin[i];
    for (int k = 0; k < SK; ++k) s += bf2f(part[(size_t)k * total + i]);
    out[i] = s;
}

// ---------------------------------------------------------------------------
// SiLU(gate) * up from gate_up partials [2][128][22016] -> act bf16 [128][11008]
// ---------------------------------------------------------------------------
__launch_bounds__(256)
__global__ void silu_mul(const u16* __restrict__ part, u16* __restrict__ act) {
    const int n = blockIdx.x * 256 + threadIdx.x;   // 0..11007
    const int m = blockIdx.y;
    const size_t plane = (size_t)M_TOK * 22016;
    const size_t base = (size_t)m * 22016;
    float g = bf2f(part[base + n]) + bf2f(part[plane + base + n]);
    float u = bf2f(part[base + n + 11008]) + bf2f(part[plane + base + n + 11008]);
    float a = g / (1.f + __expf(-g)) * u;
    act[(size_t)m * 11008 + n] = f2bf(a);
}

// ---------------------------------------------------------------------------
extern "C" void kernel_launch(void* const* d_in, const int* in_sizes, int n_in,
                              void* d_out, int out_size, void* d_ws, size_t ws_size,
                              hipStream_t stream) {
    const float* x      = (const float*)d_in[0];
    const float* ln1_w  = (const float*)d_in[1];
    const float* ln2_w  = (const float*)d_in[2];
    const int*   qkv_qw = (const int*)d_in[3];
    const int*   qkv_qz = (const int*)d_in[4];
    const float* qkv_sc = (const float*)d_in[5];
    const int*   o_qw   = (const int*)d_in[6];
    const int*   o_qz   = (const int*)d_in[7];
    const float* o_sc   = (const float*)d_in[8];
    const int*   gu_qw  = (const int*)d_in[9];
    const int*   gu_qz  = (const int*)d_in[10];
    const float* gu_sc  = (const float*)d_in[11];
    const int*   dn_qw  = (const int*)d_in[12];
    const int*   dn_qz  = (const int*)d_in[13];
    const float* dn_sc  = (const float*)d_in[14];
    float* out = (float*)d_out;

    char* ws = (char*)d_ws;
    u16*   h1   = (u16*)(ws);                       // 128x4096 bf16 : 1 MB
    u16*   qb   = (u16*)(ws + 1048576);             // 128x4096 bf16 : 1 MB
    float* res2 = (float*)(ws + 2097152);           // 128x4096 f32  : 2 MB
    u16*   h2   = (u16*)(ws + 4194304);             // 128x4096 bf16 : 1 MB
    u16*   act  = (u16*)(ws + 5242880);             // 128x11008 bf16: 2.6875 MB
    u16*   pbuf = (u16*)(ws + 8060928);             // partials, up to 11272192 B

    const int TOT = M_TOK * 4096;                   // 524288

    // h1 = rmsnorm(x, ln1)
    rmsnorm_k<<<128, 256, 0, stream>>>(x, ln1_w, h1);

    // q = h1 @ Wqkv[:, :4096]   (K=4096, SK=8, kchunk=512)
    gemm_awq<<<dim3(32, 8), 256, 0, stream>>>(h1, qkv_qw, qkv_qz, qkv_sc, pbuf,
                                              4096, 1536, 12288, 4096, 512);
    reduce_bf16<<<2048, 256, 0, stream>>>(pbuf, qb, TOT, 8);

    // attn = q @ Wo ; res2 = x + attn
    gemm_awq<<<dim3(32, 8), 256, 0, stream>>>(qb, o_qw, o_qz, o_sc, pbuf,
                                              4096, 512, 4096, 4096, 512);
    reduce_add_f32<<<2048, 256, 0, stream>>>(pbuf, x, res2, TOT, 8);

    // h2 = rmsnorm(res2, ln2)
    rmsnorm_k<<<128, 256, 0, stream>>>(res2, ln2_w, h2);

    // gate_up = h2 @ Wgu  (N=22016, SK=2, kchunk=2048)
    gemm_awq<<<dim3(172, 2), 256, 0, stream>>>(h2, gu_qw, gu_qz, gu_sc, pbuf,
                                               4096, 2752, 22016, 22016, 2048);
    silu_mul<<<dim3(43, 128), 256, 0, stream>>>(pbuf, act);

    // down = act @ Wdn  (K=11008, SK=8, kchunk=1376); out = res2 + down
    gemm_awq<<<dim3(32, 8), 256, 0, stream>>>(act, dn_qw, dn_qz, dn_sc, pbuf,
                                              11008, 512, 4096, 4096, 1376);
    reduce_add_f32<<<2048, 256, 0, stream>>>(pbuf, res2, out, TOT, 8);
}

// Round 2
// 338.949 us; speedup vs baseline: 1.0490x; 1.0490x over previous
//
#include <hip/hip_runtime.h>

typedef unsigned int   u32;
typedef unsigned short u16;

typedef __bf16 bf16x8 __attribute__((ext_vector_type(8)));
typedef float  f32x4  __attribute__((ext_vector_type(4)));

#define M_TOK 128

__device__ __forceinline__ u16 f2bf(float f) {
    u32 u = __builtin_bit_cast(u32, f);
    return (u16)((u + 0x8000u) >> 16);   // round-half-up to bf16
}
__device__ __forceinline__ float bf2f(u16 h) {
    u32 u = ((u32)h) << 16;
    return __builtin_bit_cast(float, u);
}

// LDS row layout: 80 B per row + 64 B pad every 8 rows.
// - 16B-granule aligned (b128-friendly)
// - dequant u32 writes: p-stride (8 rows) = 704 B = 176 words == 16 mod 32 -> 2-way (free)
// - A-row b128 writes / frag reads: starts cover 8 residues evenly -> balanced
__device__ __forceinline__ int rowoff(int r) { return r * 80 + (r >> 3) * 64; }

// ---------------------------------------------------------------------------
// RMSNorm: one block per token row (4096 cols), fp32 in -> bf16 out
// ---------------------------------------------------------------------------
__launch_bounds__(256)
__global__ void rmsnorm_k(const float* __restrict__ in, const float* __restrict__ w,
                          u16* __restrict__ out) {
    const int row = blockIdx.x;
    const float* x = in + (size_t)row * 4096;
    float ss = 0.f;
#pragma unroll
    for (int j = 0; j < 16; ++j) {
        float v = x[threadIdx.x + 256 * j];
        ss += v * v;
    }
#pragma unroll
    for (int off = 32; off > 0; off >>= 1) ss += __shfl_down(ss, off, 64);
    __shared__ float ws4[4];
    if ((threadIdx.x & 63) == 0) ws4[threadIdx.x >> 6] = ss;
    __syncthreads();
    float total = ws4[0] + ws4[1] + ws4[2] + ws4[3];
    float r = rsqrtf(total * (1.f / 4096.f) + 1e-6f);
    u16* o = out + (size_t)row * 4096;
#pragma unroll
    for (int j = 0; j < 16; ++j) {
        int i = threadIdx.x + 256 * j;
        o[i] = f2bf(x[i] * r * w[i]);
    }
}

// ---------------------------------------------------------------------------
// AWQ GEMM: A (bf16, 128 x K row-major) @ dequant(W) (K x N), split-K partials.
// Tile: BM=128, BN=64, BK=32. 4 waves, each 64x32 (4x2 mfma_16x16x32_bf16).
// Role split: waves 0-1 dequant B into LDS; waves 2-3 stage A into LDS.
// Depth-1 register prefetch for qw + A; per-group (G=128) hoist+prefetch of qz/sc.
// ---------------------------------------------------------------------------
__launch_bounds__(256, 3)
__global__ void gemm_awq(const u16* __restrict__ A, const int* __restrict__ qw,
                         const int* __restrict__ qz, const float* __restrict__ sc,
                         u16* __restrict__ part,
                         int Astride, int qws, int scs, int N, int K, int kchunk) {
    __shared__ __align__(16) char ldsA[11264];   // 128 rows x 32 bf16 (padded)
    __shared__ __align__(16) char ldsB[5632];    // 64 rows x 32 bf16 (padded)

    const int tid = threadIdx.x;
    const int n0 = blockIdx.x * 64;
    const int sk = blockIdx.y;
    const int kc0 = sk * kchunk;
    const int kend = min(kc0 + kchunk, K);

    const int w    = tid >> 6;
    const int lane = tid & 63;
    const int wr  = (w >> 1) * 64;      // wave m-base
    const int wc  = (w & 1) * 32;       // wave n-base
    const int q   = lane >> 4;
    const int l16 = lane & 15;

    // B-role mapping (tid < 128): k-pair kp, packed-col p (8 cols -> 64 n)
    const int kp = tid & 15;
    const int p  = (tid >> 4) & 7;
    const int pc = (n0 >> 3) + p;
    const int nb = p * 704;             // rowoff(p*8)

    // A-role mapping (tid >= 128): one row each
    const int ar = tid & 127;
    const u16* arow = A + (size_t)ar * Astride;
    char* adst = ldsA + rowoff(ar);

    f32x4 acc[4][2] = {};
    const u32 M4 = 0x0F0F0F0Fu;

    // ---- initial prefetch ----
    u32 zv = 0, w0c = 0, w1c = 0;
    float scv[8];
    uint4 a0c, a1c, a2c, a3c;
    if (tid < 128) {
        zv  = (u32)qz[(size_t)(kc0 >> 7) * qws + pc];
        const float* scp = sc + (size_t)(kc0 >> 7) * scs + n0 + p * 8;
        *(float4*)&scv[0] = *(const float4*)&scp[0];
        *(float4*)&scv[4] = *(const float4*)&scp[4];
        w0c = (u32)qw[(size_t)(kc0 + 2 * kp) * qws + pc];
        w1c = (u32)qw[(size_t)(kc0 + 2 * kp + 1) * qws + pc];
    } else {
        a0c = *(const uint4*)&arow[kc0 + 0];
        a1c = *(const uint4*)&arow[kc0 + 8];
        a2c = *(const uint4*)&arow[kc0 + 16];
        a3c = *(const uint4*)&arow[kc0 + 24];
    }

    for (int g0 = kc0; g0 < kend; g0 += 128) {
        const bool moreg = (g0 + 128) < kend;
        u32 zv_n = 0;
        float scv_n[8];
        u32 be = 0, bo = 0;
        if (tid < 128) {
            be = 0x10101010u - (zv & M4);
            bo = 0x10101010u - ((zv >> 4) & M4);
        }
#pragma unroll
        for (int s = 0; s < 4; ++s) {
            const int k0 = g0 + s * 32;
            const int kn = k0 + 32;
            if (tid < 128) {
                const u32 w0 = w0c, w1 = w1c;
                if (kn < kend) {
                    w0c = (u32)qw[(size_t)(kn + 2 * kp) * qws + pc];
                    w1c = (u32)qw[(size_t)(kn + 2 * kp + 1) * qws + pc];
                }
                if (s == 0 && moreg) {
                    zv_n = (u32)qz[(size_t)((g0 + 128) >> 7) * qws + pc];
                    const float* scp = sc + (size_t)((g0 + 128) >> 7) * scs + n0 + p * 8;
                    *(float4*)&scv_n[0] = *(const float4*)&scp[0];
                    *(float4*)&scv_n[4] = *(const float4*)&scp[4];
                }
                // dequant: biased bytes 16 + w - z in [1,31]; no carries
                const u32 d0e = (w0 & M4) + be;
                const u32 d0o = ((w0 >> 4) & M4) + bo;
                const u32 d1e = (w1 & M4) + be;
                const u32 d1o = ((w1 >> 4) & M4) + bo;
                char* bbase = ldsB + nb + kp * 4;
                auto emit = [&](int j, u32 A0, u32 A1, int b) {
                    const float scj = scv[j];
                    const float off = -16.f * scj;
                    float f0 = fmaf((float)((A0 >> (8 * b)) & 0xFFu), scj, off);
                    float f1 = fmaf((float)((A1 >> (8 * b)) & 0xFFu), scj, off);
                    u32 u0 = __builtin_bit_cast(u32, f0) + 0x8000u;
                    u32 u1 = __builtin_bit_cast(u32, f1) + 0x8000u;
                    *(u32*)(bbase + j * 80) = __builtin_amdgcn_perm(u1, u0, 0x07060302u);
                };
                // even nibbles (shift 0,8,16,24) -> j = 0,4,1,5 ; odd -> 2,6,3,7
                emit(0, d0e, d1e, 0); emit(4, d0e, d1e, 1);
                emit(1, d0e, d1e, 2); emit(5, d0e, d1e, 3);
                emit(2, d0o, d1o, 0); emit(6, d0o, d1o, 1);
                emit(3, d0o, d1o, 2); emit(7, d0o, d1o, 3);
            } else {
                const uint4 b0 = a0c, b1 = a1c, b2 = a2c, b3 = a3c;
                if (kn < kend) {
                    a0c = *(const uint4*)&arow[kn + 0];
                    a1c = *(const uint4*)&arow[kn + 8];
                    a2c = *(const uint4*)&arow[kn + 16];
                    a3c = *(const uint4*)&arow[kn + 24];
                }
                *(uint4*)(adst + 0)  = b0;
                *(uint4*)(adst + 16) = b1;
                *(uint4*)(adst + 32) = b2;
                *(uint4*)(adst + 48) = b3;
            }
            __syncthreads();

            bf16x8 af[4], bv[2];
#pragma unroll
            for (int mt = 0; mt < 4; ++mt)
                af[mt] = *(const bf16x8*)(ldsA + rowoff(wr + mt * 16 + l16) + q * 16);
#pragma unroll
            for (int nt = 0; nt < 2; ++nt)
                bv[nt] = *(const bf16x8*)(ldsB + rowoff(wc + nt * 16 + l16) + q * 16);
#pragma unroll
            for (int mt = 0; mt < 4; ++mt)
#pragma unroll
                for (int nt = 0; nt < 2; ++nt)
                    acc[mt][nt] = __builtin_amdgcn_mfma_f32_16x16x32_bf16(
                        af[mt], bv[nt], acc[mt][nt], 0, 0, 0);
            __syncthreads();
        }
        if (tid < 128 && moreg) {
            zv = zv_n;
#pragma unroll
            for (int j = 0; j < 8; ++j) scv[j] = scv_n[j];
        }
    }

    // ---- epilogue: bf16 partial store ----
    u16* pp = part + (size_t)sk * M_TOK * N;
#pragma unroll
    for (int mt = 0; mt < 4; ++mt) {
#pragma unroll
        for (int nt = 0; nt < 2; ++nt) {
            const int n = n0 + wc + nt * 16 + l16;
#pragma unroll
            for (int r = 0; r < 4; ++r) {
                const int m = wr + mt * 16 + q * 4 + r;
                pp[(size_t)m * N + n] = f2bf(acc[mt][nt][r]);
            }
        }
    }
}

// ---------------------------------------------------------------------------
// Reduce split-K bf16 partials -> bf16
// ---------------------------------------------------------------------------
__launch_bounds__(256)
__global__ void reduce_bf16(const u16* __restrict__ part, u16* __restrict__ out,
                            int total, int SK) {
    const int i = blockIdx.x * 256 + threadIdx.x;
    float s = 0.f;
    for (int k = 0; k < SK; ++k) s += bf2f(part[(size_t)k * total + i]);
    out[i] = f2bf(s);
}

// Reduce split-K bf16 partials + fp32 residual -> fp32
__launch_bounds__(256)
__global__ void reduce_add_f32(const u16* __restrict__ part, const float* __restrict__ resin,
                               float* __restrict__ out, int total, int SK) {
    const int i = blockIdx.x * 256 + threadIdx.x;
    float s = resin[i];
    for (int k = 0; k < SK; ++k) s += bf2f(part[(size_t)k * total + i]);
    out[i] = s;
}

// ---------------------------------------------------------------------------
// SiLU(gate) * up from gate_up partials [2][128][22016] -> act bf16 [128][11008]
// ---------------------------------------------------------------------------
__launch_bounds__(256)
__global__ void silu_mul(const u16* __restrict__ part, u16* __restrict__ act) {
    const int n = blockIdx.x * 256 + threadIdx.x;   // 0..11007
    const int m = blockIdx.y;
    const size_t plane = (size_t)M_TOK * 22016;
    const size_t base = (size_t)m * 22016;
    float g = bf2f(part[base + n]) + bf2f(part[plane + base + n]);
    float u = bf2f(part[base + n + 11008]) + bf2f(part[plane + base + n + 11008]);
    float a = g / (1.f + __expf(-g)) * u;
    act[(size_t)m * 11008 + n] = f2bf(a);
}

// ---------------------------------------------------------------------------
extern "C" void kernel_launch(void* const* d_in, const int* in_sizes, int n_in,
                              void* d_out, int out_size, void* d_ws, size_t ws_size,
                              hipStream_t stream) {
    const float* x      = (const float*)d_in[0];
    const float* ln1_w  = (const float*)d_in[1];
    const float* ln2_w  = (const float*)d_in[2];
    const int*   qkv_qw = (const int*)d_in[3];
    const int*   qkv_qz = (const int*)d_in[4];
    const float* qkv_sc = (const float*)d_in[5];
    const int*   o_qw   = (const int*)d_in[6];
    const int*   o_qz   = (const int*)d_in[7];
    const float* o_sc   = (const float*)d_in[8];
    const int*   gu_qw  = (const int*)d_in[9];
    const int*   gu_qz  = (const int*)d_in[10];
    const float* gu_sc  = (const float*)d_in[11];
    const int*   dn_qw  = (const int*)d_in[12];
    const int*   dn_qz  = (const int*)d_in[13];
    const float* dn_sc  = (const float*)d_in[14];
    float* out = (float*)d_out;

    // ws layout (total ~16.7 MB; R0 used 19.3 MB so this is within known capacity)
    char* ws = (char*)d_ws;
    u16*   pbuf = (u16*)(ws);                       // partials: max 11.27 MB (gu)
    u16*   slot = (u16*)(ws + 11534336);            // h1 / qb / h2 (1 MB, time-shared)
    float* res2 = (float*)(ws + 12582912);          // 2 MB fp32
    u16*   act  = (u16*)(ws + 14680064);            // 2.75 MB bf16

    const int TOT = M_TOK * 4096;                   // 524288

    // h1 = rmsnorm(x, ln1)
    rmsnorm_k<<<128, 256, 0, stream>>>(x, ln1_w, slot);

    // q = h1 @ Wqkv[:, :4096]   (K=4096, 64 n-tiles, SK=8, kchunk=512)
    gemm_awq<<<dim3(64, 8), 256, 0, stream>>>(slot, qkv_qw, qkv_qz, qkv_sc, pbuf,
                                              4096, 1536, 12288, 4096, 4096, 512);
    reduce_bf16<<<2048, 256, 0, stream>>>(pbuf, slot, TOT, 8);

    // attn = q @ Wo ; res2 = x + attn
    gemm_awq<<<dim3(64, 8), 256, 0, stream>>>(slot, o_qw, o_qz, o_sc, pbuf,
                                              4096, 512, 4096, 4096, 4096, 512);
    reduce_add_f32<<<2048, 256, 0, stream>>>(pbuf, x, res2, TOT, 8);

    // h2 = rmsnorm(res2, ln2)
    rmsnorm_k<<<128, 256, 0, stream>>>(res2, ln2_w, slot);

    // gate_up = h2 @ Wgu  (344 n-tiles, SK=2, kchunk=2048)
    gemm_awq<<<dim3(344, 2), 256, 0, stream>>>(slot, gu_qw, gu_qz, gu_sc, pbuf,
                                               4096, 2752, 22016, 22016, 4096, 2048);
    silu_mul<<<dim3(43, 128), 256, 0, stream>>>(pbuf, act);

    // down = act @ Wdn  (K=11008, SK=8, kchunk=1408 last=1152); out = res2 + down
    gemm_awq<<<dim3(64, 8), 256, 0, stream>>>(act, dn_qw, dn_qz, dn_sc, pbuf,
                                              11008, 512, 4096, 4096, 11008, 1408);
    reduce_add_f32<<<2048, 256, 0, stream>>>(pbuf, res2, out, TOT, 8);
}